// Round 7
// baseline (405.672 us; speedup 1.0000x reference)
//
#include <hip/hip_runtime.h>
#include <hip/hip_bf16.h>
#include <hip/hip_fp16.h>
#include <math.h>

#define N_NODES 100000
#define N_EDGES 1600000
#define NBLK_SCAN 391   // ceil(100000/256)
// IN=128, HD=128, H=4, D=32

typedef __attribute__((ext_vector_type(8))) short bf16x8;
typedef __attribute__((ext_vector_type(4))) float f32x4;

__device__ __forceinline__ short f2bf_s(float x) {
    __hip_bfloat16 b = __float2bfloat16(x);
    return *reinterpret_cast<short*>(&b);
}
__device__ __forceinline__ __half2 bc2(unsigned u) {
    return *reinterpret_cast<__half2*>(&u);
}
__device__ __forceinline__ unsigned bcu(__half2 h) {
    return *reinterpret_cast<unsigned*>(&h);
}

// ============================================================
// prep: [dst histogram] + [W transpose -> bf16]
//   blocks 0..6249: histogram over 1.6M edges
//   blocks 6250..6505: Wtb[m][c][k] = W[m][k][c]
// ============================================================
__global__ __launch_bounds__(256) void prep(
    const int* __restrict__ dst,
    const float* __restrict__ Wq, const float* __restrict__ Wk,
    const float* __restrict__ Wv, const float* __restrict__ Ws,
    unsigned short* __restrict__ Wtb, int* __restrict__ counts)
{
    int bid = blockIdx.x;
    if (bid < 6250) {
        int e = bid * 256 + threadIdx.x;
        atomicAdd(&counts[dst[e]], 1);
    } else {
        int j = (bid - 6250) * 256 + threadIdx.x;   // [0, 65536)
        int m = j >> 14;
        int rem = j & 16383;
        int c = rem >> 7;
        int kk = rem & 127;
        const float* W = (m == 0) ? Wq : (m == 1) ? Wk : (m == 2) ? Wv : Ws;
        Wtb[j] = (unsigned short)f2bf_s(W[(size_t)kk * 128 + c]);
    }
}

// ============================================================
// CSR scan (2 kernels; add_back folded away via end-pointer trick)
// ============================================================
__global__ __launch_bounds__(256) void scan_block(
    const int* __restrict__ counts, int* __restrict__ offs, int* __restrict__ bsums)
{
    __shared__ int s[256];
    int i = blockIdx.x * 256 + threadIdx.x;
    int x = (i < N_NODES) ? counts[i] : 0;
    s[threadIdx.x] = x;
    __syncthreads();
    #pragma unroll
    for (int o = 1; o < 256; o <<= 1) {
        int t = (threadIdx.x >= o) ? s[threadIdx.x - o] : 0;
        __syncthreads();
        s[threadIdx.x] += t;
        __syncthreads();
    }
    if (i < N_NODES) offs[i] = s[threadIdx.x] - x;   // block-local exclusive
    if (threadIdx.x == 255) bsums[blockIdx.x] = s[255];
}

__global__ __launch_bounds__(512) void scan_sums(
    int* __restrict__ bsums, int* __restrict__ bscan)
{
    __shared__ int s[512];
    int i = threadIdx.x;
    int x = (i < NBLK_SCAN) ? bsums[i] : 0;
    s[i] = x;
    __syncthreads();
    #pragma unroll
    for (int o = 1; o < 512; o <<= 1) {
        int t = (i >= o) ? s[i - o] : 0;
        __syncthreads();
        s[i] += t;
        __syncthreads();
    }
    if (i < NBLK_SCAN) bscan[i] = s[i] - x;
}

// ============================================================
// fused: [MFMA GEMM, blocks 0..3124] || [scatter, blocks 3125..9374]
//   gemm: 32 rows/block, wave = matrix; fp32 feat -> in-reg bf16; fp16 out
//   scatter: pos = atomicAdd(&offs[dN],1) + bscan[dN>>8]
//     (post-scatter: offs[n]+bscan[n>>8] == end(n); start(n) = end(n-1))
// ============================================================
__global__ __launch_bounds__(256) void gemm_scatter(
    const float* __restrict__ feat, const unsigned short* __restrict__ Wtb,
    const float* __restrict__ bq, const float* __restrict__ bk,
    const float* __restrict__ bv, const float* __restrict__ bs,
    __half* __restrict__ qh, __half* __restrict__ kh,
    __half* __restrict__ vh, __half* __restrict__ skh,
    const int* __restrict__ src, const int* __restrict__ dst,
    int* __restrict__ offs, const int* __restrict__ bscan,
    int* __restrict__ sorted_src)
{
    if (blockIdx.x >= 3125) {
        int e = (blockIdx.x - 3125) * 256 + threadIdx.x;   // exact 1.6M
        int dN = dst[e];
        int pos = atomicAdd(&offs[dN], 1) + bscan[dN >> 8];
        sorted_src[pos] = src[e];
        return;
    }

    const int mat = threadIdx.x >> 6;    // wave = matrix
    const int l   = threadIdx.x & 63;
    const int lr  = l & 15;
    const int lg  = l >> 4;
    const int r0  = blockIdx.x * 32;     // 3125 * 32 = 100000 exact
    const float* bias = (mat == 0) ? bq : (mat == 1) ? bk : (mat == 2) ? bv : bs;
    __half* outp      = (mat == 0) ? qh : (mat == 1) ? kh : (mat == 2) ? vh : skh;

    f32x4 acc[2][8];
    #pragma unroll
    for (int i = 0; i < 2; i++)
        #pragma unroll
        for (int j = 0; j < 8; j++) acc[i][j] = (f32x4){0.f, 0.f, 0.f, 0.f};

    #pragma unroll
    for (int ks = 0; ks < 4; ks++) {
        const int k0 = ks * 32 + lg * 8;
        bf16x8 a[2], b[8];
        #pragma unroll
        for (int rf = 0; rf < 2; rf++) {
            const float* fp = feat + (size_t)(r0 + rf * 16 + lr) * 128 + k0;
            float4 f0 = ((const float4*)fp)[0];
            float4 f1 = ((const float4*)fp)[1];
            a[rf] = (bf16x8){f2bf_s(f0.x), f2bf_s(f0.y), f2bf_s(f0.z), f2bf_s(f0.w),
                             f2bf_s(f1.x), f2bf_s(f1.y), f2bf_s(f1.z), f2bf_s(f1.w)};
        }
        #pragma unroll
        for (int cf = 0; cf < 8; cf++) {
            int col = cf * 16 + lr;
            b[cf] = *(const bf16x8*)(Wtb + ((size_t)mat * 128 + col) * 128 + k0);
        }
        #pragma unroll
        for (int rf = 0; rf < 2; rf++)
            #pragma unroll
            for (int cf = 0; cf < 8; cf++)
                acc[rf][cf] = __builtin_amdgcn_mfma_f32_16x16x32_bf16(
                    a[rf], b[cf], acc[rf][cf], 0, 0, 0);
    }

    // C/D layout: col = lane&15, row = (lane>>4)*4 + reg
    #pragma unroll
    for (int rf = 0; rf < 2; rf++) {
        #pragma unroll
        for (int cf = 0; cf < 8; cf++) {
            int col = cf * 16 + lr;
            float bv_ = bias[col];
            #pragma unroll
            for (int reg = 0; reg < 4; reg++) {
                int row = r0 + rf * 16 + lg * 4 + reg;
                outp[(size_t)row * 128 + col] = __float2half(acc[rf][cf][reg] + bv_);
            }
        }
    }
}

// ============================================================
// fused dst-centric aggregation + gate + LN + PReLU
//   one wave per node; lane = (quarter, c): quarter-wave per edge
//   depth-3 software pipeline (2 groups prefetched), packed fp16 math
// ============================================================
__global__ __launch_bounds__(256) void node_fused(
    const __half* __restrict__ qh, const __half* __restrict__ kh,
    const __half* __restrict__ vh, const __half* __restrict__ skh,
    const int* __restrict__ offs, const int* __restrict__ bscan,
    const int* __restrict__ sorted_src,
    const float* __restrict__ wg, const float* __restrict__ bg,
    const float* __restrict__ gamma, const float* __restrict__ beta,
    const float* __restrict__ pa, float* __restrict__ out)
{
    int wid = threadIdx.x >> 6;
    int l   = threadIdx.x & 63;
    int qtr = l >> 4;
    int c   = l & 15;
    int n = blockIdx.x * 4 + wid;
    if (n >= N_NODES) return;

    int end   = offs[n] + bscan[n >> 8];
    int start = (n == 0) ? 0 : (offs[n - 1] + bscan[(n - 1) >> 8]);

    const uint4* qrow = (const uint4*)qh;   // row = 16 uint4 chunks
    const uint4* vrow = (const uint4*)vh;

    uint4 kp = ((const uint4*)kh)[(size_t)n * 16 + c];
    uint4 sp4 = ((const uint4*)skh)[(size_t)n * 16 + c];   // hoisted skip load
    __half2 kk0 = bc2(kp.x), kk1 = bc2(kp.y), kk2 = bc2(kp.z), kk3 = bc2(kp.w);

    float den = 0.f;
    __half2 ag0 = bc2(0u), ag1 = bc2(0u), ag2 = bc2(0u), ag3 = bc2(0u);
    const float C = 0.25503483f;   // (1/sqrt(32)) * log2(e)

    // depth-3 pipeline over 4-edge groups
    uint4 qA, vA, qB, vB;
    int base = start;
    {
        int cl = min(base + qtr, end - 1);
        int s = sorted_src[cl];
        qA = qrow[(size_t)s * 16 + c];
        vA = vrow[(size_t)s * 16 + c];
    }
    bool hasB = (base + 4) < end;
    if (hasB) {
        int cl = min(base + 4 + qtr, end - 1);
        int s = sorted_src[cl];
        qB = qrow[(size_t)s * 16 + c];
        vB = vrow[(size_t)s * 16 + c];
    }
    for (;;) {
        int baseC = base + 8;
        bool hasC = baseC < end;
        uint4 qC, vC;
        if (hasC) {
            int cl = min(baseC + qtr, end - 1);
            int s = sorted_src[cl];
            qC = qrow[(size_t)s * 16 + c];
            vC = vrow[(size_t)s * 16 + c];
        }
        // compute group A
        __half2 d2 = __hmul2(bc2(qA.x), kk0);
        d2 = __hfma2(bc2(qA.y), kk1, d2);
        d2 = __hfma2(bc2(qA.z), kk2, d2);
        d2 = __hfma2(bc2(qA.w), kk3, d2);
        d2 = __hadd2(d2, bc2(__shfl_xor(bcu(d2), 1)));
        d2 = __hadd2(d2, bc2(__shfl_xor(bcu(d2), 2)));
        float d = __low2float(d2) + __high2float(d2);
        float e = (base + qtr < end) ? __builtin_amdgcn_exp2f(d * C) : 0.f;
        den += e;
        __half2 e2 = __float2half2_rn(e);
        ag0 = __hfma2(e2, bc2(vA.x), ag0);
        ag1 = __hfma2(e2, bc2(vA.y), ag1);
        ag2 = __hfma2(e2, bc2(vA.z), ag2);
        ag3 = __hfma2(e2, bc2(vA.w), ag3);
        if (!hasB) break;
        base += 4;
        qA = qB; vA = vB; qB = qC; vB = vC; hasB = hasC;
    }

    // merge the four quarters
    den += __shfl_xor(den, 16);
    den += __shfl_xor(den, 32);
    ag0 = __hadd2(ag0, bc2(__shfl_xor(bcu(ag0), 16)));
    ag1 = __hadd2(ag1, bc2(__shfl_xor(bcu(ag1), 16)));
    ag2 = __hadd2(ag2, bc2(__shfl_xor(bcu(ag2), 16)));
    ag3 = __hadd2(ag3, bc2(__shfl_xor(bcu(ag3), 16)));
    ag0 = __hadd2(ag0, bc2(__shfl_xor(bcu(ag0), 32)));
    ag1 = __hadd2(ag1, bc2(__shfl_xor(bcu(ag1), 32)));
    ag2 = __hadd2(ag2, bc2(__shfl_xor(bcu(ag2), 32)));
    ag3 = __hadd2(ag3, bc2(__shfl_xor(bcu(ag3), 32)));

    float rd = 1.f / den;
    float r[8];
    r[0] = __low2float(ag0) * rd; r[1] = __high2float(ag0) * rd;
    r[2] = __low2float(ag1) * rd; r[3] = __high2float(ag1) * rd;
    r[4] = __low2float(ag2) * rd; r[5] = __high2float(ag2) * rd;
    r[6] = __low2float(ag3) * rd; r[7] = __high2float(ag3) * rd;

    float s[8];
    s[0] = __low2float(bc2(sp4.x)); s[1] = __high2float(bc2(sp4.x));
    s[2] = __low2float(bc2(sp4.y)); s[3] = __high2float(bc2(sp4.y));
    s[4] = __low2float(bc2(sp4.z)); s[5] = __high2float(bc2(sp4.z));
    s[6] = __low2float(bc2(sp4.w)); s[7] = __high2float(bc2(sp4.w));

    const float4* wgf = (const float4*)wg;
    float4 w0a = wgf[2 * c],      w0b = wgf[2 * c + 1];
    float4 w1a = wgf[32 + 2 * c], w1b = wgf[32 + 2 * c + 1];
    float4 w2a = wgf[64 + 2 * c], w2b = wgf[64 + 2 * c + 1];
    float w0[8] = {w0a.x, w0a.y, w0a.z, w0a.w, w0b.x, w0b.y, w0b.z, w0b.w};
    float w1[8] = {w1a.x, w1a.y, w1a.z, w1a.w, w1b.x, w1b.y, w1b.z, w1b.w};
    float w2[8] = {w2a.x, w2a.y, w2a.z, w2a.w, w2b.x, w2b.y, w2b.z, w2b.w};

    float gs = 0.f;
    #pragma unroll
    for (int j = 0; j < 8; j++)
        gs += s[j] * w0[j] + r[j] * w1[j] + (s[j] - r[j]) * w2[j];
    gs += __shfl_xor(gs, 1);
    gs += __shfl_xor(gs, 2);
    gs += __shfl_xor(gs, 4);
    gs += __shfl_xor(gs, 8);
    float g = 1.f / (1.f + __builtin_amdgcn_exp2f(-(gs + bg[0]) * 1.4426950408889634f));

    #pragma unroll
    for (int j = 0; j < 8; j++) r[j] = g * s[j] + (1.f - g) * r[j];

    float mu = 0.f;
    #pragma unroll
    for (int j = 0; j < 8; j++) mu += r[j];
    mu += __shfl_xor(mu, 1);
    mu += __shfl_xor(mu, 2);
    mu += __shfl_xor(mu, 4);
    mu += __shfl_xor(mu, 8);
    mu *= (1.f / 128.f);

    float var = 0.f;
    #pragma unroll
    for (int j = 0; j < 8; j++) { float e0 = r[j] - mu; var += e0 * e0; }
    var += __shfl_xor(var, 1);
    var += __shfl_xor(var, 2);
    var += __shfl_xor(var, 4);
    var += __shfl_xor(var, 8);
    var *= (1.f / 128.f);
    float inv = rsqrtf(var + 1e-5f);

    if (qtr == 0) {
        float4 ga = ((const float4*)gamma)[2 * c], gb = ((const float4*)gamma)[2 * c + 1];
        float4 ba = ((const float4*)beta)[2 * c],  bb = ((const float4*)beta)[2 * c + 1];
        float gm[8] = {ga.x, ga.y, ga.z, ga.w, gb.x, gb.y, gb.z, gb.w};
        float bt[8] = {ba.x, ba.y, ba.z, ba.w, bb.x, bb.y, bb.z, bb.w};
        float al = pa[0];
        float y[8];
        #pragma unroll
        for (int j = 0; j < 8; j++) {
            float t = (r[j] - mu) * inv * gm[j] + bt[j];
            y[j] = (t > 0.f) ? t : al * t;
        }
        float4* op = (float4*)(out + (size_t)n * 128 + c * 8);
        op[0] = (float4){y[0], y[1], y[2], y[3]};
        op[1] = (float4){y[4], y[5], y[6], y[7]};
    }
}

// ============================================================
extern "C" void kernel_launch(void* const* d_in, const int* in_sizes, int n_in,
                              void* d_out, int out_size, void* d_ws, size_t ws_size,
                              hipStream_t stream) {
    const float* feat  = (const float*)d_in[0];
    const int*   src   = (const int*)d_in[1];
    const int*   dst   = (const int*)d_in[2];
    const float* Wq    = (const float*)d_in[3];
    const float* bq    = (const float*)d_in[4];
    const float* Wk    = (const float*)d_in[5];
    const float* bk    = (const float*)d_in[6];
    const float* Wv    = (const float*)d_in[7];
    const float* bv    = (const float*)d_in[8];
    const float* Wsk   = (const float*)d_in[9];
    const float* bsk   = (const float*)d_in[10];
    const float* Wg    = (const float*)d_in[11];
    const float* bg    = (const float*)d_in[12];
    const float* gamma = (const float*)d_in[13];
    const float* beta  = (const float*)d_in[14];
    const float* pa    = (const float*)d_in[15];
    float* out = (float*)d_out;

    char* p = (char*)d_ws;
    const size_t NH = (size_t)N_NODES * 128 * 2;   // 25.6 MB fp16 plane
    __half* qh  = (__half*)p;  p += NH;
    __half* kh  = (__half*)p;  p += NH;
    __half* vh  = (__half*)p;  p += NH;
    __half* skh = (__half*)p;  p += NH;
    unsigned short* Wtb = (unsigned short*)p;  p += (size_t)4 * 128 * 128 * 2;
    int* sorted_src = (int*)p;  p += (size_t)N_EDGES * 4;
    int* counts     = (int*)p;  p += (size_t)N_NODES * 4;
    int* offs       = (int*)p;  p += (size_t)N_NODES * 4;
    int* bsums      = (int*)p;  p += 4096;
    int* bscan      = (int*)p;  p += 4096;

    hipMemsetAsync(counts, 0, (size_t)N_NODES * 4, stream);

    prep<<<6506, 256, 0, stream>>>(dst, Wq, Wk, Wv, Wsk, Wtb, counts);
    scan_block<<<NBLK_SCAN, 256, 0, stream>>>(counts, offs, bsums);
    scan_sums<<<1, 512, 0, stream>>>(bsums, bscan);
    gemm_scatter<<<9375, 256, 0, stream>>>(feat, Wtb, bq, bk, bv, bsk,
                                           qh, kh, vh, skh,
                                           src, dst, offs, bscan, sorted_src);
    node_fused<<<(N_NODES + 3) / 4, 256, 0, stream>>>(qh, kh, vh, skh, offs, bscan,
                                                      sorted_src,
                                                      Wg, bg, gamma, beta, pa, out);
}